// Round 8
// baseline (209.388 us; speedup 1.0000x reference)
//
#include <hip/hip_runtime.h>

// Causal self-attention, S=4096, E=D=1024, fp32 in/out.
// R18: combine proven configs. y-GEMM back to 128x128 split-K=2 (R13's
//   best per-block form, 47.2us @3/CU) but now co-launched with V as
//   128x64 tiles (512+512 = 1024 blocks, 32KB static LDS -> 5/CU cap,
//   4/CU actual = all resident; R13 had only 3/CU). Separate fence-free
//   k_redsplit(y) (R15-proven). XCD-balanced 64y+64V per XCD.
//   R17 accounting: non-yv time ~144us; yv still largest dispatch (58.9).
//   Residency is THE lever for this latency-serialized structure
//   (R12->R13: +50% residency -> -25% time).
//   RULE (R14): no device-scope fences in hot kernels on gfx950.

typedef unsigned short u16;
typedef unsigned int   u32;
typedef __bf16 bf16x8 __attribute__((ext_vector_type(8)));
typedef float  f32x16 __attribute__((ext_vector_type(16)));
typedef u16    u16x8  __attribute__((ext_vector_type(8)));

#define SLEN 4096
#define EDIM 1024
#define CCAP 32

__device__ __forceinline__ u16 f2bf(float x) {
    union { float f; u32 u; } c; c.f = x;
    return (u16)((c.u + 0x7FFFu + ((c.u >> 16) & 1u)) >> 16);
}
__device__ __forceinline__ float bf2f(u16 h) {
    union { u32 u; float f; } c; c.u = ((u32)h) << 16;
    return c.f;
}

__device__ __forceinline__ void gll16(const u16* g, u16* l) {
    __builtin_amdgcn_global_load_lds(
        (const __attribute__((address_space(1))) void*)g,
        (__attribute__((address_space(3))) void*)l, 16, 0, 0);
}

__device__ __forceinline__ void split_f4(const float* __restrict__ in,
                                         u16* __restrict__ hi,
                                         u16* __restrict__ lo, int i) {
    const float4 v = reinterpret_cast<const float4*>(in)[i];
    u16 h0 = f2bf(v.x), h1 = f2bf(v.y), h2 = f2bf(v.z), h3 = f2bf(v.w);
    reinterpret_cast<ushort4*>(hi)[i] = make_ushort4(h0, h1, h2, h3);
    reinterpret_cast<ushort4*>(lo)[i] =
        make_ushort4(f2bf(v.x - bf2f(h0)), f2bf(v.y - bf2f(h1)),
                     f2bf(v.z - bf2f(h2)), f2bf(v.w - bf2f(h3)));
}

// ---------------- GEMM core: 128x128 tile, BK=32, 32x32x16 MFMA ------------
// LDS row r x 4 slots of 8 u16; physical slot p of row r holds K-chunk
// p^(r&3) (pre-swizzled global source + swizzled read, rule-21 form).
template <int TERMS, bool DBUF>
__device__ __forceinline__ void gemm_core(
    u16* smem,
    const u16* __restrict__ Ah, const u16* __restrict__ Al,
    const u16* __restrict__ Bh, const u16* __restrict__ Bl,
    int K, int kbeg, int kend, int rowA0, int rowB0,
    int tid, f32x16 (&acc)[2][2]) {
    constexpr int NB = (TERMS == 3) ? 2 : 1;
    constexpr int TSZ = 8192 * NB;  // u16 per LDS buffer
    const int lane = tid & 63, wv = tid >> 6;
    const int wm = (wv >> 1) * 64, wn = (wv & 1) * 64;
    const int l31 = lane & 31, lh = lane >> 5;
    const int swz = l31 & 3;

    const u16* srcs[2 * NB];
    if constexpr (TERMS == 3) {
        srcs[0] = Ah + (size_t)rowA0 * K;
        srcs[1] = Al + (size_t)rowA0 * K;
        srcs[2] = Bh + (size_t)rowB0 * K;
        srcs[3] = Bl + (size_t)rowB0 * K;
    } else {
        srcs[0] = Ah + (size_t)rowA0 * K;
        srcs[1] = Bh + (size_t)rowB0 * K;
    }

    auto stage = [&](u16* dst, int k0) {
#pragma unroll
        for (int i = 0; i < 4 * NB; i++) {
            int c = ((i & 1) << 8) + (wv << 6) + lane;
            int m = c >> 2;
            int kb = (c & 3) ^ (m & 3);  // source pre-swizzle
            const u16* g = srcs[i >> 1] + (size_t)m * K + (k0 + kb * 8);
            u16* l = dst + (size_t)((i << 8) + (wv << 6) + lane) * 8;
            gll16(g, l);
        }
    };

    auto compute = [&](const u16* bc) {
        const u16* sAh = bc;
        const u16* sAl = bc + 4096;
        const u16* sBh = bc + ((TERMS == 3) ? 8192 : 4096);
        const u16* sBl = bc + 12288;
#pragma unroll
        for (int ks = 0; ks < 2; ks++) {
            const int so = ((((ks << 1) | lh) ^ swz) << 3);
            bf16x8 a[2], b[2];
#pragma unroll
            for (int i = 0; i < 2; i++) {
                a[i] = *(const bf16x8*)(sAh + (wm + i * 32 + l31) * 32 + so);
                b[i] = *(const bf16x8*)(sBh + (wn + i * 32 + l31) * 32 + so);
            }
            if constexpr (TERMS == 3) {
                bf16x8 al2[2], bl2[2];
#pragma unroll
                for (int i = 0; i < 2; i++) {
                    al2[i] = *(const bf16x8*)(sAl + (wm + i * 32 + l31) * 32 + so);
                    bl2[i] = *(const bf16x8*)(sBl + (wn + i * 32 + l31) * 32 + so);
                }
#pragma unroll
                for (int mi = 0; mi < 2; mi++)
#pragma unroll
                    for (int ni = 0; ni < 2; ni++) {
                        acc[mi][ni] = __builtin_amdgcn_mfma_f32_32x32x16_bf16(a[mi], b[ni], acc[mi][ni], 0, 0, 0);
                        acc[mi][ni] = __builtin_amdgcn_mfma_f32_32x32x16_bf16(a[mi], bl2[ni], acc[mi][ni], 0, 0, 0);
                        acc[mi][ni] = __builtin_amdgcn_mfma_f32_32x32x16_bf16(al2[mi], b[ni], acc[mi][ni], 0, 0, 0);
                    }
            } else {
#pragma unroll
                for (int mi = 0; mi < 2; mi++)
#pragma unroll
                    for (int ni = 0; ni < 2; ni++)
                        acc[mi][ni] = __builtin_amdgcn_mfma_f32_32x32x16_bf16(a[mi], b[ni], acc[mi][ni], 0, 0, 0);
            }
        }
    };

    if constexpr (DBUF) {
        const int nsteps = (kend - kbeg) >> 5;
        stage(smem, kbeg);
        int cur = 0;
        for (int t = 0; t < nsteps; t++) {
            u16* bc = smem + (cur ? TSZ : 0);
            if (t + 1 < nsteps) {
                stage(smem + (cur ? 0 : TSZ), kbeg + (t << 5) + 32);
                if constexpr (TERMS == 3)
                    asm volatile("s_waitcnt vmcnt(8)" ::: "memory");
                else
                    asm volatile("s_waitcnt vmcnt(4)" ::: "memory");
            } else {
                asm volatile("s_waitcnt vmcnt(0)" ::: "memory");
            }
            __builtin_amdgcn_s_barrier();
            __builtin_amdgcn_s_setprio(1);
            compute(bc);
            __builtin_amdgcn_s_setprio(0);
            asm volatile("" ::: "memory");
            __builtin_amdgcn_s_barrier();
            cur ^= 1;
        }
    } else {
        for (int k0 = kbeg; k0 < kend; k0 += 32) {
            stage(smem, k0);
            __syncthreads();
            compute(smem);
            __syncthreads();
        }
    }
}

// ---------------- GEMM core 2: 128x64 tile, BK=32 (V-part of yv) -----------
// Waves 2x2 over 64x32 sub-tiles; acc[2]. Same XOR swizzle.
template <int TERMS>
__device__ __forceinline__ void gemm_core64(
    u16* smem,
    const u16* __restrict__ Ah, const u16* __restrict__ Al,
    const u16* __restrict__ Bh, const u16* __restrict__ Bl,
    int K, int rowA0, int rowB0, int tid, f32x16 (&acc)[2]) {
    const int lane = tid & 63, wv = tid >> 6;
    const int wm = (wv >> 1) * 64, wn = (wv & 1) * 32;
    const int l31 = lane & 31, lh = lane >> 5;
    const int swz = l31 & 3;

    const u16* sA0 = Ah + (size_t)rowA0 * K;
    const u16* sA1 = (TERMS == 3) ? Al + (size_t)rowA0 * K : nullptr;
    const u16* sB0 = Bh + (size_t)rowB0 * K;
    const u16* sB1 = (TERMS == 3) ? Bl + (size_t)rowB0 * K : nullptr;
    constexpr int BB = (TERMS == 3) ? 8192 : 4096;

    for (int k0 = 0; k0 < K; k0 += 32) {
#pragma unroll
        for (int i = 0; i < 2; i++) {
            int c = (i << 8) + tid;
            int m = c >> 2;
            int kb = (c & 3) ^ (m & 3);
            gll16(sA0 + (size_t)m * K + (k0 + kb * 8), smem + c * 8);
            if constexpr (TERMS == 3)
                gll16(sA1 + (size_t)m * K + (k0 + kb * 8), smem + 4096 + c * 8);
        }
        {
            int c = tid;
            int m = c >> 2;
            int kb = (c & 3) ^ (m & 3);
            gll16(sB0 + (size_t)m * K + (k0 + kb * 8), smem + BB + c * 8);
            if constexpr (TERMS == 3)
                gll16(sB1 + (size_t)m * K + (k0 + kb * 8), smem + BB + 2048 + c * 8);
        }
        __syncthreads();

        const u16* sAh = smem;
        const u16* sAl = smem + 4096;
        const u16* sBh = smem + BB;
        const u16* sBl = smem + BB + 2048;
#pragma unroll
        for (int ks = 0; ks < 2; ks++) {
            const int so = ((((ks << 1) | lh) ^ swz) << 3);
            bf16x8 a0 = *(const bf16x8*)(sAh + (wm + l31) * 32 + so);
            bf16x8 a1 = *(const bf16x8*)(sAh + (wm + 32 + l31) * 32 + so);
            bf16x8 b0 = *(const bf16x8*)(sBh + (wn + l31) * 32 + so);
            if constexpr (TERMS == 3) {
                bf16x8 al0 = *(const bf16x8*)(sAl + (wm + l31) * 32 + so);
                bf16x8 al1 = *(const bf16x8*)(sAl + (wm + 32 + l31) * 32 + so);
                bf16x8 bl0 = *(const bf16x8*)(sBl + (wn + l31) * 32 + so);
                acc[0] = __builtin_amdgcn_mfma_f32_32x32x16_bf16(a0, b0, acc[0], 0, 0, 0);
                acc[0] = __builtin_amdgcn_mfma_f32_32x32x16_bf16(a0, bl0, acc[0], 0, 0, 0);
                acc[0] = __builtin_amdgcn_mfma_f32_32x32x16_bf16(al0, b0, acc[0], 0, 0, 0);
                acc[1] = __builtin_amdgcn_mfma_f32_32x32x16_bf16(a1, b0, acc[1], 0, 0, 0);
                acc[1] = __builtin_amdgcn_mfma_f32_32x32x16_bf16(a1, bl0, acc[1], 0, 0, 0);
                acc[1] = __builtin_amdgcn_mfma_f32_32x32x16_bf16(al1, b0, acc[1], 0, 0, 0);
            } else {
                acc[0] = __builtin_amdgcn_mfma_f32_32x32x16_bf16(a0, b0, acc[0], 0, 0, 0);
                acc[1] = __builtin_amdgcn_mfma_f32_32x32x16_bf16(a1, b0, acc[1], 0, 0, 0);
            }
        }
        __syncthreads();
    }
}

// C/D 32x32 layout: col = lane&31, row = (r&3) + 8*(r>>2) + 4*(lane>>5)
#define EPILOGUE_32(BODY)                                                    \
    {                                                                        \
    const int lane = threadIdx.x & 63, wv = threadIdx.x >> 6;                \
    const int wm = (wv >> 1) * 64, wn = (wv & 1) * 64;                       \
    const int l31 = lane & 31, lh4 = (lane >> 5) * 4;                        \
    _Pragma("unroll")                                                        \
    for (int mi = 0; mi < 2; mi++)                                           \
        _Pragma("unroll")                                                    \
        for (int ni = 0; ni < 2; ni++)                                       \
            _Pragma("unroll")                                                \
            for (int r = 0; r < 16; r++) {                                   \
                int row = wm + mi * 32 + (r & 3) + 8 * (r >> 2) + lh4;       \
                int col = wn + ni * 32 + l31;                                \
                float val = acc[mi][ni][r];                                  \
                BODY                                                         \
            }                                                                \
    }

#define EPILOGUE_64(ACC, BODY)                                               \
    {                                                                        \
    const int lane = threadIdx.x & 63, wv = threadIdx.x >> 6;                \
    const int wm = (wv >> 1) * 64, wn = (wv & 1) * 32;                       \
    const int l31 = lane & 31, lh4 = (lane >> 5) * 4;                        \
    _Pragma("unroll")                                                        \
    for (int mi = 0; mi < 2; mi++)                                           \
        _Pragma("unroll")                                                    \
        for (int r = 0; r < 16; r++) {                                       \
            int row = wm + mi * 32 + (r & 3) + 8 * (r >> 2) + lh4;           \
            int col = wn + l31;                                              \
            float val = ACC[mi][r];                                          \
            BODY                                                             \
        }                                                                    \
    }

// ---- fused prep: split x (b<4096), Wq (<5120), Wk (<6144), Wv^T (rest) ----
__global__ __launch_bounds__(256) void k_prep(
    const float* __restrict__ x, const float* __restrict__ Wq,
    const float* __restrict__ Wk, const float* __restrict__ Wv,
    u16* __restrict__ xh, u16* __restrict__ xl,
    u16* __restrict__ Wqh, u16* __restrict__ Wql,
    u16* __restrict__ Wkh, u16* __restrict__ Wkl,
    u16* __restrict__ Wvth) {
    __shared__ float tile[32][33];
    const int b = blockIdx.x, tid = threadIdx.x;
    if (b < 4096) {
        split_f4(x, xh, xl, b * 256 + tid);
    } else if (b < 5120) {
        split_f4(Wq, Wqh, Wql, (b - 4096) * 256 + tid);
    } else if (b < 6144) {
        split_f4(Wk, Wkh, Wkl, (b - 5120) * 256 + tid);
    } else {
        int t = b - 6144;
        int tx = tid & 31, ty = tid >> 5;
        int c0 = (t & 31) * 32, r0 = (t >> 5) * 32;
#pragma unroll
        for (int r = 0; r < 4; r++)
            tile[ty + r * 8][tx] = Wv[(size_t)(r0 + ty + r * 8) * EDIM + (c0 + tx)];
        __syncthreads();
#pragma unroll
        for (int r = 0; r < 4; r++)
            Wvth[(size_t)(c0 + ty + r * 8) * EDIM + (r0 + tx)] =
                f2bf(tile[tx][ty + r * 8]);
    }
}

// ---- Mt partials: Mp[z] = Wk*Wq^T over K-slice z (split-K=8) --------------
__global__ __launch_bounds__(256) void k_gemm_m(
    const u16* __restrict__ Wkh, const u16* __restrict__ Wkl,
    const u16* __restrict__ Wqh, const u16* __restrict__ Wql,
    float* __restrict__ Mp) {
    __shared__ u16 smem[32768];
    f32x16 acc[2][2] = {};
    const int rowA0 = blockIdx.y * 128, rowB0 = blockIdx.x * 128;
    const int kbeg = blockIdx.z * 128;
    float* Mz = Mp + (size_t)blockIdx.z * EDIM * EDIM;
    gemm_core<3, true>(smem, Wkh, Wkl, Wqh, Wql, EDIM, kbeg, kbeg + 128, rowA0, rowB0, threadIdx.x, acc);
    EPILOGUE_32({ Mz[(size_t)(rowA0 + row) * EDIM + (rowB0 + col)] = val; })
}

// ---- reduce nsrc fp32 partials (stride4 float4 apart) + split hi/lo -------
__global__ __launch_bounds__(256) void k_redsplit(
    const float* __restrict__ base, int stride4, int nsrc,
    u16* __restrict__ hi, u16* __restrict__ lo, int n4) {
    int i = blockIdx.x * 256 + threadIdx.x;
    if (i >= n4) return;
    float4 v = reinterpret_cast<const float4*>(base)[i];
    for (int s = 1; s < nsrc; s++) {
        float4 a = reinterpret_cast<const float4*>(base)[(size_t)s * stride4 + i];
        v.x += a.x; v.y += a.y; v.z += a.z; v.w += a.w;
    }
    u16 h0 = f2bf(v.x), h1 = f2bf(v.y), h2 = f2bf(v.z), h3 = f2bf(v.w);
    reinterpret_cast<ushort4*>(hi)[i] = make_ushort4(h0, h1, h2, h3);
    reinterpret_cast<ushort4*>(lo)[i] =
        make_ushort4(f2bf(v.x - bf2f(h0)), f2bf(v.y - bf2f(h1)),
                     f2bf(v.z - bf2f(h2)), f2bf(v.w - bf2f(h3)));
}

// ---- merged: b<512: y 128x128 split-K=2 fp32 partials; else V 128x64 ------
// 1024 blocks, 32KB static LDS -> 5/CU cap, 4/CU actual (ALL resident).
// XCD-balanced: each XCD gets 64 y + 64 V blocks.
__global__ __launch_bounds__(256) void k_gemm_yv(
    const u16* __restrict__ xh, const u16* __restrict__ xl,
    const u16* __restrict__ Mth, const u16* __restrict__ Mtl,
    const u16* __restrict__ Wvth,
    float* __restrict__ yp, u16* __restrict__ Vb) {
    __shared__ u16 smem[16384];  // 32KB
    const int b0 = blockIdx.x;
    const int xcd = b0 & 7, j = b0 >> 3;
    const int b = (j < 64) ? (xcd * 64 + j) : (512 + xcd * 64 + (j - 64));
    if (b < 512) {
        f32x16 acc[2][2] = {};
        int s = b >> 8, r = b & 255;
        int tm = r >> 3, tn = r & 7;
        gemm_core<3, false>(smem, xh, xl, Mth, Mtl, EDIM, s * 512, s * 512 + 512,
                            tm * 128, tn * 128, threadIdx.x, acc);
        float* Py = yp + (size_t)s * SLEN * EDIM;
        EPILOGUE_32({
            Py[(size_t)(tm * 128 + row) * EDIM + (tn * 128 + col)] = val;
        })
    } else {
        f32x16 acc2[2] = {};
        int b2 = b - 512;
        int tm = b2 >> 4, tn = b2 & 15;  // V[m][n] = sum_k x[m][k] Wv[k][n]
        gemm_core64<1>(smem, xh, nullptr, Wvth, nullptr, EDIM, tm * 128, tn * 64,
                       threadIdx.x, acc2);
        EPILOGUE_64(acc2, {
            Vb[(size_t)(tm * 128 + row) * EDIM + (tn * 64 + col)] = f2bf(val);
        })
    }
}

// ---- APPROX S = yh*xh^T /32, tri tiles, split-K=2, bf16 packed halves -----
__global__ __launch_bounds__(256) void k_sa(
    const u16* __restrict__ yh, const u16* __restrict__ xh,
    u16* __restrict__ Sh0, u16* __restrict__ Sh1) {
    __shared__ u16 smem[16384];
    int b0 = blockIdx.x;
    int b = (b0 & 7) * 132 + (b0 >> 3);  // bijective (1056 % 8 == 0)
    int half = (b >= 528) ? 1 : 0;
    int t = b - half * 528;
    int ti = (int)((sqrtf(8.0f * (float)t + 1.0f) - 1.0f) * 0.5f);
    while ((ti + 1) * (ti + 2) / 2 <= t) ti++;
    while (ti * (ti + 1) / 2 > t) ti--;
    int tm = ti, tn = t - ti * (ti + 1) / 2;
    f32x16 acc[2][2] = {};
    gemm_core<1, true>(smem, yh, nullptr, xh, nullptr, EDIM, half * 512, half * 512 + 512,
                       tm * 128, tn * 128, threadIdx.x, acc);
    u16* Cb = (half ? Sh1 : Sh0) + (size_t)t * 16384;
    EPILOGUE_32({ Cb[row * 128 + col] = f2bf(val * 0.03125f); })
}

// ---- finish: per row -- approx max, candidates (max-64), exact fp32 dots,
// ---- softmax over candidates, V gather. One block per row. ----------------
__global__ __launch_bounds__(256) void k_finish(
    const u16* __restrict__ Sh0, const u16* __restrict__ Sh1,
    const u16* __restrict__ yh, const u16* __restrict__ yl,
    const u16* __restrict__ xh, const u16* __restrict__ xl,
    const u16* __restrict__ Vb, float* __restrict__ out) {
    __shared__ u16 syh[EDIM], syl[EDIM];  // 4KB y row (hi/lo)
    __shared__ float red[4];
    __shared__ int cidx[CCAP];
    __shared__ float cs[CCAP];
    __shared__ int cnt;

    const int row = blockIdx.x, tid = threadIdx.x;
    const int lane = tid & 63, wid = tid >> 6;
    const int n = row + 1;
    const int tm = row >> 7, rl = row & 127;
    const size_t base = (size_t)(tm * (tm + 1) / 2) * 16384 + rl * 128;
    const u16* s0 = Sh0 + base;
    const u16* s1 = Sh1 + base;

    // y row to LDS (256 thr x ushort4 = 1024)
    ((ushort4*)syh)[tid] = ((const ushort4*)(yh + (size_t)row * EDIM))[tid];
    ((ushort4*)syl)[tid] = ((const ushort4*)(yl + (size_t)row * EDIM))[tid];
    if (tid == 0) cnt = 0;

    // approx logits in registers (16/thread) + row max
    float vals[16];
    float m = -3.0e38f;
#pragma unroll
    for (int it = 0; it < 16; it++) {
        int j = tid + it * 256;
        float v = -3.0e38f;
        if (j < n) {
            size_t idx = (size_t)(j >> 7) * 16384 + (j & 127);
            v = bf2f(s0[idx]) + bf2f(s1[idx]);
        }
        vals[it] = v;
        m = fmaxf(m, v);
    }
#pragma unroll
    for (int o = 32; o; o >>= 1) m = fmaxf(m, __shfl_xor(m, o));
    if (lane == 0) red[wid] = m;
    __syncthreads();
    m = fmaxf(fmaxf(red[0], red[1]), fmaxf(red[2], red[3]));
    __syncthreads();

    // candidate scan: approx s > max - 64 captures all exact s > max_ex - 17
    float thr = m - 64.0f;
#pragma unroll
    for (int it = 0; it < 16; it++) {
        if (vals[it] > thr) {  // implies j < n (sentinel is -3e38)
            int pos = atomicAdd(&cnt, 1);
            if (pos < CCAP) cidx[pos] = tid + it * 256;
        }
    }
    __syncthreads();
    int C = min(cnt, CCAP);

    // exact logits: one wave per candidate, fp32 dot (yh+yl)*(xh+xl)
    for (int k = wid; k < C; k += 4) {
        int j = cidx[k];
        const u16* xhj = xh + (size_t)j * EDIM;
        const u16* xlj = xl + (size_t)j * EDIM;
        const int e0 = lane * 16;
        u16x8 xv0 = *(const u16x8*)(xhj + e0);
        u16x8 xv1 = *(const u16x8*)(xhj + e0 + 8);
        u16x8 xw0 = *(const u16x8*)(xlj + e0);
        u16x8 xw1 = *(const u16x8*)(xlj + e0 + 8);
        u16x8 yv0 = *(const u16x8*)(syh + e0);
        u16x8 yv1 = *(const u16x8*)(syh + e0 + 8);
        u16x8 yw0 = *(const u16x8*)(syl + e0);
        u16x8 yw1 = *(const u16x8*)(syl + e0 + 8);
        float a = 0.f;
#pragma unroll
        for (int e = 0; e < 8; e++) {
            a += (bf2f(yv0[e]) + bf2f(yw0[e])) * (bf2f(xv0[e]) + bf2f(xw0[e]));
            a += (bf2f(yv1[e]) + bf2f(yw1[e])) * (bf2f(xv1[e]) + bf2f(xw1[e]));
        }
#pragma unroll
        for (int o = 32; o; o >>= 1) a += __shfl_xor(a, o);
        if (lane == 0) cs[k] = a * 0.03125f;
    }
    __syncthreads();

    // softmax over candidates (redundant per-thread over <=32 entries)
    float me = -3.0e38f;
    for (int k = 0; k < C; k++) me = fmaxf(me, cs[k]);
    float S = 0.f;
    for (int k = 0; k < C; k++) S += __expf(cs[k] - me);
    float invS = 1.0f / S;

    // gather: out[row] = sum_k p_k * V[j_k]; each thread owns 4 cols
    const int d0 = tid * 4;
    float4 o4 = make_float4(0.f, 0.f, 0.f, 0.f);
    for (int k = 0; k < C; k++) {
        float p = __expf(cs[k] - me) * invS;
        ushort4 v = *(const ushort4*)(Vb + (size_t)cidx[k] * EDIM + d0);
        o4.x += p * bf2f(v.x);
        o4.y += p * bf2f(v.y);
        o4.z += p * bf2f(v.z);
        o4.w += p * bf2f(v.w);
    }
    *(float4*)(out + (size_t)row * EDIM + d0) = o4;
}

// ---------------------------------------------------------------------------
extern "C" void kernel_launch(void* const* d_in, const int* in_sizes, int n_in,
                              void* d_out, int out_size, void* d_ws, size_t ws_size,
                              hipStream_t stream) {
    const float* x  = (const float*)d_in[0];
    const float* Wq = (const float*)d_in[1];
    const float* Wk = (const float*)d_in[2];
    const float* Wv = (const float*)d_in[3];
    float* out = (float*)d_out;
    char* ws = (char*)d_ws;
    const size_t MB = 1024 * 1024;

    // persistent
    u16* xh = (u16*)(ws + 0 * MB);     // 8MB, live to finish
    u16* xl = (u16*)(ws + 8 * MB);     // 8MB
    u16* yh = (u16*)(ws + 16 * MB);    // 8MB
    u16* yl = (u16*)(ws + 24 * MB);    // 8MB
    u16* Vb = (u16*)(ws + 32 * MB);    // 8MB row-major bf16
    // [40,76): time-multiplexed scratch:
    //   (a) k_gemm_m partials Mp: 8 x 4MB = [40,72)   (dead after k_redsplit#1)
    //   (b) k_gemm_yv y partials: 2 x 16MB = [40,72)  (dead after k_redsplit#2)
    //   (c) k_sa output Sh0 [40,58) / Sh1 [58,76)     (read by k_finish)
    float* Mp  = (float*)(ws + 40 * MB);
    float* yp  = (float*)(ws + 40 * MB);
    u16* Sh0 = (u16*)(ws + 40 * MB);
    u16* Sh1 = (u16*)(ws + 58 * MB);
    // transients [76,106)
    u16* Wqh  = (u16*)(ws + 76 * MB);
    u16* Wql  = (u16*)(ws + 78 * MB);
    u16* Wkh  = (u16*)(ws + 80 * MB);
    u16* Wkl  = (u16*)(ws + 82 * MB);
    u16* Wvth = (u16*)(ws + 84 * MB);
    u16* Mth  = (u16*)(ws + 102 * MB);
    u16* Mtl  = (u16*)(ws + 104 * MB);     // -106

    dim3 b256(256);

    // 1) fused prep: split x, Wq, Wk; transpose Wv
    k_prep<<<7168, b256, 0, stream>>>(x, Wq, Wk, Wv, xh, xl, Wqh, Wql, Wkh, Wkl, Wvth);

    // 2) Mt = Wk*Wq^T: 8 K-slice partials (512 blocks = 2/CU)
    k_gemm_m<<<dim3(8, 8, 8), b256, 0, stream>>>(Wkh, Wkl, Wqh, Wql, Mp);

    // 3) reduce 8 + split Mt
    k_redsplit<<<1024, b256, 0, stream>>>(Mp, (EDIM * EDIM) / 4, 8, Mth, Mtl,
                                          (EDIM * EDIM) / 4);

    // 4) y partials (split-K=2) + V = x*Wv (128x64)   (1024 blocks = 4/CU)
    k_gemm_yv<<<1024, b256, 0, stream>>>(xh, xl, Mth, Mtl, Wvth, yp, Vb);

    // 5) reduce 2 + split y -> yh/yl
    k_redsplit<<<4096, b256, 0, stream>>>(yp, (SLEN * EDIM) / 4, 2, yh, yl,
                                          (SLEN * EDIM) / 4);

    // 6) approx S = yh*xh^T /32 (bf16, split-K=2 halves)
    k_sa<<<1056, b256, 0, stream>>>(yh, xh, Sh0, Sh1);

    // 7) finish: scan + exact re-dot + softmax + gather
    k_finish<<<SLEN, b256, 0, stream>>>(Sh0, Sh1, yh, yl, xh, xl, Vb, out);
}

// Round 9
// 202.058 us; speedup vs baseline: 1.0363x; 1.0363x over previous
//
#include <hip/hip_runtime.h>

// Causal self-attention, S=4096, E=D=1024, fp32 in/out.
// R19: revert yv to R15 form (proven 47-48us floor; R16-R18 variants all
//   worse). New lever: heterogeneous co-schedule. k_prep split into
//   k_prep_w (Wq/Wk splits, the only true dep of gemm_m) and k_mix:
//   blocks 0-511 = gemm_m (splitK=8, single-buffer 32KB), blocks 512+ =
//   x-split (4096) + Wv-transpose (1024, LDS aliased). Streaming blocks
//   fill gemm_m's latency stalls (m114 MFMA/VALU co-schedule mechanism,
//   applied across block types). Numerically identical to R15.
//   RULE (R14): no device-scope fences in hot kernels on gfx950.

typedef unsigned short u16;
typedef unsigned int   u32;
typedef __bf16 bf16x8 __attribute__((ext_vector_type(8)));
typedef float  f32x16 __attribute__((ext_vector_type(16)));
typedef u16    u16x8  __attribute__((ext_vector_type(8)));

#define SLEN 4096
#define EDIM 1024
#define CCAP 32

__device__ __forceinline__ u16 f2bf(float x) {
    union { float f; u32 u; } c; c.f = x;
    return (u16)((c.u + 0x7FFFu + ((c.u >> 16) & 1u)) >> 16);
}
__device__ __forceinline__ float bf2f(u16 h) {
    union { u32 u; float f; } c; c.u = ((u32)h) << 16;
    return c.f;
}

__device__ __forceinline__ void gll16(const u16* g, u16* l) {
    __builtin_amdgcn_global_load_lds(
        (const __attribute__((address_space(1))) void*)g,
        (__attribute__((address_space(3))) void*)l, 16, 0, 0);
}

__device__ __forceinline__ void split_f4(const float* __restrict__ in,
                                         u16* __restrict__ hi,
                                         u16* __restrict__ lo, int i) {
    const float4 v = reinterpret_cast<const float4*>(in)[i];
    u16 h0 = f2bf(v.x), h1 = f2bf(v.y), h2 = f2bf(v.z), h3 = f2bf(v.w);
    reinterpret_cast<ushort4*>(hi)[i] = make_ushort4(h0, h1, h2, h3);
    reinterpret_cast<ushort4*>(lo)[i] =
        make_ushort4(f2bf(v.x - bf2f(h0)), f2bf(v.y - bf2f(h1)),
                     f2bf(v.z - bf2f(h2)), f2bf(v.w - bf2f(h3)));
}

// ---------------- GEMM core: 128x128 tile, BK=32, 32x32x16 MFMA ------------
// LDS row r x 4 slots of 8 u16; physical slot p of row r holds K-chunk
// p^(r&3) (pre-swizzled global source + swizzled read, rule-21 form).
template <int TERMS, bool DBUF>
__device__ __forceinline__ void gemm_core(
    u16* smem,
    const u16* __restrict__ Ah, const u16* __restrict__ Al,
    const u16* __restrict__ Bh, const u16* __restrict__ Bl,
    int K, int kbeg, int kend, int rowA0, int rowB0,
    int tid, f32x16 (&acc)[2][2]) {
    constexpr int NB = (TERMS == 3) ? 2 : 1;
    constexpr int TSZ = 8192 * NB;  // u16 per LDS buffer
    const int lane = tid & 63, wv = tid >> 6;
    const int wm = (wv >> 1) * 64, wn = (wv & 1) * 64;
    const int l31 = lane & 31, lh = lane >> 5;
    const int swz = l31 & 3;

    const u16* srcs[2 * NB];
    if constexpr (TERMS == 3) {
        srcs[0] = Ah + (size_t)rowA0 * K;
        srcs[1] = Al + (size_t)rowA0 * K;
        srcs[2] = Bh + (size_t)rowB0 * K;
        srcs[3] = Bl + (size_t)rowB0 * K;
    } else {
        srcs[0] = Ah + (size_t)rowA0 * K;
        srcs[1] = Bh + (size_t)rowB0 * K;
    }

    auto stage = [&](u16* dst, int k0) {
#pragma unroll
        for (int i = 0; i < 4 * NB; i++) {
            int c = ((i & 1) << 8) + (wv << 6) + lane;
            int m = c >> 2;
            int kb = (c & 3) ^ (m & 3);  // source pre-swizzle
            const u16* g = srcs[i >> 1] + (size_t)m * K + (k0 + kb * 8);
            u16* l = dst + (size_t)((i << 8) + (wv << 6) + lane) * 8;
            gll16(g, l);
        }
    };

    auto compute = [&](const u16* bc) {
        const u16* sAh = bc;
        const u16* sAl = bc + 4096;
        const u16* sBh = bc + ((TERMS == 3) ? 8192 : 4096);
        const u16* sBl = bc + 12288;
#pragma unroll
        for (int ks = 0; ks < 2; ks++) {
            const int so = ((((ks << 1) | lh) ^ swz) << 3);
            bf16x8 a[2], b[2];
#pragma unroll
            for (int i = 0; i < 2; i++) {
                a[i] = *(const bf16x8*)(sAh + (wm + i * 32 + l31) * 32 + so);
                b[i] = *(const bf16x8*)(sBh + (wn + i * 32 + l31) * 32 + so);
            }
            if constexpr (TERMS == 3) {
                bf16x8 al2[2], bl2[2];
#pragma unroll
                for (int i = 0; i < 2; i++) {
                    al2[i] = *(const bf16x8*)(sAl + (wm + i * 32 + l31) * 32 + so);
                    bl2[i] = *(const bf16x8*)(sBl + (wn + i * 32 + l31) * 32 + so);
                }
#pragma unroll
                for (int mi = 0; mi < 2; mi++)
#pragma unroll
                    for (int ni = 0; ni < 2; ni++) {
                        acc[mi][ni] = __builtin_amdgcn_mfma_f32_32x32x16_bf16(a[mi], b[ni], acc[mi][ni], 0, 0, 0);
                        acc[mi][ni] = __builtin_amdgcn_mfma_f32_32x32x16_bf16(a[mi], bl2[ni], acc[mi][ni], 0, 0, 0);
                        acc[mi][ni] = __builtin_amdgcn_mfma_f32_32x32x16_bf16(al2[mi], b[ni], acc[mi][ni], 0, 0, 0);
                    }
            } else {
#pragma unroll
                for (int mi = 0; mi < 2; mi++)
#pragma unroll
                    for (int ni = 0; ni < 2; ni++)
                        acc[mi][ni] = __builtin_amdgcn_mfma_f32_32x32x16_bf16(a[mi], b[ni], acc[mi][ni], 0, 0, 0);
            }
        }
    };

    if constexpr (DBUF) {
        const int nsteps = (kend - kbeg) >> 5;
        stage(smem, kbeg);
        int cur = 0;
        for (int t = 0; t < nsteps; t++) {
            u16* bc = smem + (cur ? TSZ : 0);
            if (t + 1 < nsteps) {
                stage(smem + (cur ? 0 : TSZ), kbeg + (t << 5) + 32);
                if constexpr (TERMS == 3)
                    asm volatile("s_waitcnt vmcnt(8)" ::: "memory");
                else
                    asm volatile("s_waitcnt vmcnt(4)" ::: "memory");
            } else {
                asm volatile("s_waitcnt vmcnt(0)" ::: "memory");
            }
            __builtin_amdgcn_s_barrier();
            __builtin_amdgcn_s_setprio(1);
            compute(bc);
            __builtin_amdgcn_s_setprio(0);
            asm volatile("" ::: "memory");
            __builtin_amdgcn_s_barrier();
            cur ^= 1;
        }
    } else {
        for (int k0 = kbeg; k0 < kend; k0 += 32) {
            stage(smem, k0);
            __syncthreads();
            compute(smem);
            __syncthreads();
        }
    }
}

// C/D 32x32 layout: col = lane&31, row = (r&3) + 8*(r>>2) + 4*(lane>>5)
#define EPILOGUE_32(BODY)                                                    \
    {                                                                        \
    const int lane = threadIdx.x & 63, wv = threadIdx.x >> 6;                \
    const int wm = (wv >> 1) * 64, wn = (wv & 1) * 64;                       \
    const int l31 = lane & 31, lh4 = (lane >> 5) * 4;                        \
    _Pragma("unroll")                                                        \
    for (int mi = 0; mi < 2; mi++)                                           \
        _Pragma("unroll")                                                    \
        for (int ni = 0; ni < 2; ni++)                                       \
            _Pragma("unroll")                                                \
            for (int r = 0; r < 16; r++) {                                   \
                int row = wm + mi * 32 + (r & 3) + 8 * (r >> 2) + lh4;       \
                int col = wn + ni * 32 + l31;                                \
                float val = acc[mi][ni][r];                                  \
                BODY                                                         \
            }                                                                \
    }

// ---- W-prep: split Wq (b<1024), Wk (rest). Must precede k_mix. ------------
__global__ __launch_bounds__(256) void k_prep_w(
    const float* __restrict__ Wq, const float* __restrict__ Wk,
    u16* __restrict__ Wqh, u16* __restrict__ Wql,
    u16* __restrict__ Wkh, u16* __restrict__ Wkl) {
    const int b = blockIdx.x, tid = threadIdx.x;
    if (b < 1024) {
        split_f4(Wq, Wqh, Wql, b * 256 + tid);
    } else {
        split_f4(Wk, Wkh, Wkl, (b - 1024) * 256 + tid);
    }
}

// ---- mixed: b<512 = Mt partials (Wk*Wq^T, splitK=8, single-buffer);
// ----        b<4608 = x split; else Wv transpose. Independent halves ------
// Heterogeneous co-schedule: streaming blocks fill gemm stalls.
__global__ __launch_bounds__(256) void k_mix(
    const float* __restrict__ x, const float* __restrict__ Wv,
    const u16* __restrict__ Wkh, const u16* __restrict__ Wkl,
    const u16* __restrict__ Wqh, const u16* __restrict__ Wql,
    u16* __restrict__ xh, u16* __restrict__ xl,
    u16* __restrict__ Wvth, float* __restrict__ Mp) {
    __shared__ u16 smem[16384];  // 32KB; prep blocks alias/ignore
    const int b = blockIdx.x, tid = threadIdx.x;
    if (b < 512) {
        // gemm_m: bz = K-slice, (by,bx) = tile; all 512 combos covered
        const int bz = b >> 6, by = (b >> 3) & 7, bx = b & 7;
        f32x16 acc[2][2] = {};
        const int rowA0 = by * 128, rowB0 = bx * 128;
        const int kbeg = bz * 128;
        float* Mz = Mp + (size_t)bz * EDIM * EDIM;
        gemm_core<3, false>(smem, Wkh, Wkl, Wqh, Wql, EDIM, kbeg, kbeg + 128,
                            rowA0, rowB0, tid, acc);
        EPILOGUE_32({ Mz[(size_t)(rowA0 + row) * EDIM + (rowB0 + col)] = val; })
    } else if (b < 4608) {
        split_f4(x, xh, xl, (b - 512) * 256 + tid);
    } else {
        // Wv transpose via LDS tile aliased onto smem (4.2KB < 32KB)
        float (*tile)[33] = reinterpret_cast<float(*)[33]>(smem);
        int t = b - 4608;
        int tx = tid & 31, ty = tid >> 5;
        int c0 = (t & 31) * 32, r0 = (t >> 5) * 32;
#pragma unroll
        for (int r = 0; r < 4; r++)
            tile[ty + r * 8][tx] = Wv[(size_t)(r0 + ty + r * 8) * EDIM + (c0 + tx)];
        __syncthreads();
#pragma unroll
        for (int r = 0; r < 4; r++)
            Wvth[(size_t)(c0 + ty + r * 8) * EDIM + (r0 + tx)] =
                f2bf(tile[tx][ty + r * 8]);
    }
}

// ---- reduce nsrc fp32 partials (stride4 float4 apart) + split hi/lo -------
__global__ __launch_bounds__(256) void k_redsplit(
    const float* __restrict__ base, int stride4, int nsrc,
    u16* __restrict__ hi, u16* __restrict__ lo, int n4) {
    int i = blockIdx.x * 256 + threadIdx.x;
    if (i >= n4) return;
    float4 v = reinterpret_cast<const float4*>(base)[i];
    for (int s = 1; s < nsrc; s++) {
        float4 a = reinterpret_cast<const float4*>(base)[(size_t)s * stride4 + i];
        v.x += a.x; v.y += a.y; v.z += a.z; v.w += a.w;
    }
    u16 h0 = f2bf(v.x), h1 = f2bf(v.y), h2 = f2bf(v.z), h3 = f2bf(v.w);
    reinterpret_cast<ushort4*>(hi)[i] = make_ushort4(h0, h1, h2, h3);
    reinterpret_cast<ushort4*>(lo)[i] =
        make_ushort4(f2bf(v.x - bf2f(h0)), f2bf(v.y - bf2f(h1)),
                     f2bf(v.z - bf2f(h2)), f2bf(v.w - bf2f(h3)));
}

// ---- merged: b<512: y split-K=2 fp32 partials; else V = x*Wv --------------
// grid 768 = 3 blocks/CU (R15-proven form). XCD-balanced: 64 y + 32 V /XCD.
__global__ __launch_bounds__(256) void k_gemm_yv(
    const u16* __restrict__ xh, const u16* __restrict__ xl,
    const u16* __restrict__ Mth, const u16* __restrict__ Mtl,
    const u16* __restrict__ Wvth,
    float* __restrict__ yp, u16* __restrict__ Vb) {
    __shared__ u16 smem[16384];  // 32KB: single-buffer
    f32x16 acc[2][2] = {};
    const int b0 = blockIdx.x;
    const int xcd = b0 & 7, j = b0 >> 3;
    const int b = (j < 64) ? (xcd * 64 + j) : (512 + xcd * 32 + (j - 64));
    if (b < 512) {
        int s = b >> 8, r = b & 255;
        int tm = r >> 3, tn = r & 7;
        gemm_core<3, false>(smem, xh, xl, Mth, Mtl, EDIM, s * 512, s * 512 + 512,
                            tm * 128, tn * 128, threadIdx.x, acc);
        float* Py = yp + (size_t)s * SLEN * EDIM;
        EPILOGUE_32({
            Py[(size_t)(tm * 128 + row) * EDIM + (tn * 128 + col)] = val;
        })
    } else {
        int b2 = b - 512;
        int tm = b2 >> 3, tn = b2 & 7;  // V[m][n] = sum_k x[m][k] Wv[k][n]
        gemm_core<1, false>(smem, xh, nullptr, Wvth, nullptr, EDIM, 0, EDIM,
                            tm * 128, tn * 128, threadIdx.x, acc);
        EPILOGUE_32({
            Vb[(size_t)(tm * 128 + row) * EDIM + (tn * 128 + col)] = f2bf(val);
        })
    }
}

// ---- APPROX S = yh*xh^T /32, tri tiles, split-K=2, bf16 packed halves -----
__global__ __launch_bounds__(256) void k_sa(
    const u16* __restrict__ yh, const u16* __restrict__ xh,
    u16* __restrict__ Sh0, u16* __restrict__ Sh1) {
    __shared__ u16 smem[16384];
    int b0 = blockIdx.x;
    int b = (b0 & 7) * 132 + (b0 >> 3);  // bijective (1056 % 8 == 0)
    int half = (b >= 528) ? 1 : 0;
    int t = b - half * 528;
    int ti = (int)((sqrtf(8.0f * (float)t + 1.0f) - 1.0f) * 0.5f);
    while ((ti + 1) * (ti + 2) / 2 <= t) ti++;
    while (ti * (ti + 1) / 2 > t) ti--;
    int tm = ti, tn = t - ti * (ti + 1) / 2;
    f32x16 acc[2][2] = {};
    gemm_core<1, true>(smem, yh, nullptr, xh, nullptr, EDIM, half * 512, half * 512 + 512,
                       tm * 128, tn * 128, threadIdx.x, acc);
    u16* Cb = (half ? Sh1 : Sh0) + (size_t)t * 16384;
    EPILOGUE_32({ Cb[row * 128 + col] = f2bf(val * 0.03125f); })
}

// ---- finish: per row -- approx max, candidates (max-64), exact fp32 dots,
// ---- softmax over candidates, V gather. One block per row. ----------------
__global__ __launch_bounds__(256) void k_finish(
    const u16* __restrict__ Sh0, const u16* __restrict__ Sh1,
    const u16* __restrict__ yh, const u16* __restrict__ yl,
    const u16* __restrict__ xh, const u16* __restrict__ xl,
    const u16* __restrict__ Vb, float* __restrict__ out) {
    __shared__ u16 syh[EDIM], syl[EDIM];  // 4KB y row (hi/lo)
    __shared__ float red[4];
    __shared__ int cidx[CCAP];
    __shared__ float cs[CCAP];
    __shared__ int cnt;

    const int row = blockIdx.x, tid = threadIdx.x;
    const int lane = tid & 63, wid = tid >> 6;
    const int n = row + 1;
    const int tm = row >> 7, rl = row & 127;
    const size_t base = (size_t)(tm * (tm + 1) / 2) * 16384 + rl * 128;
    const u16* s0 = Sh0 + base;
    const u16* s1 = Sh1 + base;

    // y row to LDS (256 thr x ushort4 = 1024)
    ((ushort4*)syh)[tid] = ((const ushort4*)(yh + (size_t)row * EDIM))[tid];
    ((ushort4*)syl)[tid] = ((const ushort4*)(yl + (size_t)row * EDIM))[tid];
    if (tid == 0) cnt = 0;

    // approx logits in registers (16/thread) + row max
    float vals[16];
    float m = -3.0e38f;
#pragma unroll
    for (int it = 0; it < 16; it++) {
        int j = tid + it * 256;
        float v = -3.0e38f;
        if (j < n) {
            size_t idx = (size_t)(j >> 7) * 16384 + (j & 127);
            v = bf2f(s0[idx]) + bf2f(s1[idx]);
        }
        vals[it] = v;
        m = fmaxf(m, v);
    }
#pragma unroll
    for (int o = 32; o; o >>= 1) m = fmaxf(m, __shfl_xor(m, o));
    if (lane == 0) red[wid] = m;
    __syncthreads();
    m = fmaxf(fmaxf(red[0], red[1]), fmaxf(red[2], red[3]));
    __syncthreads();

    // candidate scan: approx s > max - 64 captures all exact s > max_ex - 17
    float thr = m - 64.0f;
#pragma unroll
    for (int it = 0; it < 16; it++) {
        if (vals[it] > thr) {  // implies j < n (sentinel is -3e38)
            int pos = atomicAdd(&cnt, 1);
            if (pos < CCAP) cidx[pos] = tid + it * 256;
        }
    }
    __syncthreads();
    int C = min(cnt, CCAP);

    // exact logits: one wave per candidate, fp32 dot (yh+yl)*(xh+xl)
    for (int k = wid; k < C; k += 4) {
        int j = cidx[k];
        const u16* xhj = xh + (size_t)j * EDIM;
        const u16* xlj = xl + (size_t)j * EDIM;
        const int e0 = lane * 16;
        u16x8 xv0 = *(const u16x8*)(xhj + e0);
        u16x8 xv1 = *(const u16x8*)(xhj + e0 + 8);
        u16x8 xw0 = *(const u16x8*)(xlj + e0);
        u16x8 xw1 = *(const u16x8*)(xlj + e0 + 8);
        u16x8 yv0 = *(const u16x8*)(syh + e0);
        u16x8 yv1 = *(const u16x8*)(syh + e0 + 8);
        u16x8 yw0 = *(const u16x8*)(syl + e0);
        u16x8 yw1 = *(const u16x8*)(syl + e0 + 8);
        float a = 0.f;
#pragma unroll
        for (int e = 0; e < 8; e++) {
            a += (bf2f(yv0[e]) + bf2f(yw0[e])) * (bf2f(xv0[e]) + bf2f(xw0[e]));
            a += (bf2f(yv1[e]) + bf2f(yw1[e])) * (bf2f(xv1[e]) + bf2f(xw1[e]));
        }
#pragma unroll
        for (int o = 32; o; o >>= 1) a += __shfl_xor(a, o);
        if (lane == 0) cs[k] = a * 0.03125f;
    }
    __syncthreads();

    // softmax over candidates (redundant per-thread over <=32 entries)
    float me = -3.0e38f;
    for (int k = 0; k < C; k++) me = fmaxf(me, cs[k]);
    float S = 0.f;
    for (int k = 0; k < C; k++) S += __expf(cs[k] - me);
    float invS = 1.0f / S;

    // gather: out[row] = sum_k p_k * V[j_k]; each thread owns 4 cols
    const int d0 = tid * 4;
    float4 o4 = make_float4(0.f, 0.f, 0.f, 0.f);
    for (int k = 0; k < C; k++) {
        float p = __expf(cs[k] - me) * invS;
        ushort4 v = *(const ushort4*)(Vb + (size_t)cidx[k] * EDIM + d0);
        o4.x += p * bf2f(v.x);
        o4.y += p * bf2f(v.y);
        o4.z += p * bf2f(v.z);
        o4.w += p * bf2f(v.w);
    }
    *(float4*)(out + (size_t)row * EDIM + d0) = o4;
}

// ---------------------------------------------------------------------------
extern "C" void kernel_launch(void* const* d_in, const int* in_sizes, int n_in,
                              void* d_out, int out_size, void* d_ws, size_t ws_size,
                              hipStream_t stream) {
    const float* x  = (const float*)d_in[0];
    const float* Wq = (const float*)d_in[1];
    const float* Wk = (const float*)d_in[2];
    const float* Wv = (const float*)d_in[3];
    float* out = (float*)d_out;
    char* ws = (char*)d_ws;
    const size_t MB = 1024 * 1024;

    // persistent
    u16* xh = (u16*)(ws + 0 * MB);     // 8MB, live to finish
    u16* xl = (u16*)(ws + 8 * MB);     // 8MB
    u16* yh = (u16*)(ws + 16 * MB);    // 8MB
    u16* yl = (u16*)(ws + 24 * MB);    // 8MB
    u16* Vb = (u16*)(ws + 32 * MB);    // 8MB row-major bf16
    // [40,76): time-multiplexed scratch:
    //   (a) k_mix Mt partials Mp: 8 x 4MB = [40,72)   (dead after k_redsplit#1)
    //   (b) k_gemm_yv y partials: 2 x 16MB = [40,72)  (dead after k_redsplit#2)
    //   (c) k_sa output Sh0 [40,58) / Sh1 [58,76)     (read by k_finish)
    float* Mp  = (float*)(ws + 40 * MB);
    float* yp  = (float*)(ws + 40 * MB);
    u16* Sh0 = (u16*)(ws + 40 * MB);
    u16* Sh1 = (u16*)(ws + 58 * MB);
    // transients [76,106)
    u16* Wqh  = (u16*)(ws + 76 * MB);
    u16* Wql  = (u16*)(ws + 78 * MB);
    u16* Wkh  = (u16*)(ws + 80 * MB);
    u16* Wkl  = (u16*)(ws + 82 * MB);
    u16* Wvth = (u16*)(ws + 84 * MB);
    u16* Mth  = (u16*)(ws + 102 * MB);
    u16* Mtl  = (u16*)(ws + 104 * MB);     // -106

    dim3 b256(256);

    // 1) W-prep: split Wq, Wk (only true dependency of the M-GEMM)
    k_prep_w<<<2048, b256, 0, stream>>>(Wq, Wk, Wqh, Wql, Wkh, Wkl);

    // 2) mixed: Mt partials (512 gemm blocks) + x split + Wv transpose
    k_mix<<<5632, b256, 0, stream>>>(x, Wv, Wkh, Wkl, Wqh, Wql,
                                     xh, xl, Wvth, Mp);

    // 3) reduce 8 + split Mt
    k_redsplit<<<1024, b256, 0, stream>>>(Mp, (EDIM * EDIM) / 4, 8, Mth, Mtl,
                                          (EDIM * EDIM) / 4);

    // 4) y partials (split-K=2) + V = x*Wv   (768 blocks = 3/CU)
    k_gemm_yv<<<768, b256, 0, stream>>>(xh, xl, Mth, Mtl, Wvth, yp, Vb);

    // 5) reduce 2 + split y -> yh/yl
    k_redsplit<<<4096, b256, 0, stream>>>(yp, (SLEN * EDIM) / 4, 2, yh, yl,
                                          (SLEN * EDIM) / 4);

    // 6) approx S = yh*xh^T /32 (bf16, split-K=2 halves)
    k_sa<<<1056, b256, 0, stream>>>(yh, xh, Sh0, Sh1);

    // 7) finish: scan + exact re-dot + softmax + gather
    k_finish<<<SLEN, b256, 0, stream>>>(Sh0, Sh1, yh, yl, xh, xl, Vb, out);
}